// Round 1
// baseline (209.664 us; speedup 1.0000x reference)
//
#include <hip/hip_runtime.h>

// Problem constants (B, C, K, H, W) = (32, 256, 64, 56, 56)
constexpr int BB  = 32;
constexpr int CC  = 256;
constexpr int HWN = 56 * 56;      // 3136 elements per channel plane
constexpr int HW4 = HWN / 4;      // 784 float4 per plane

// Build inverse map: inv[c] = position of c in vulnerable_idx, else -1.
// Single block; C=256 threads covers both init and scatter.
__global__ void build_inv_kernel(const int* __restrict__ vidx, int K,
                                 int* __restrict__ inv) {
    int t = threadIdx.x;
    if (t < CC) inv[t] = -1;
    __syncthreads();
    if (t < K) inv[vidx[t]] = t;
}

__global__ __launch_bounds__(256) void edac_kernel(
    const float* __restrict__ mainp,
    const float* __restrict__ dupp,
    const float* __restrict__ lov,
    const float* __restrict__ hiv,
    const int*   __restrict__ inv,
    float*       __restrict__ out,
    int K)
{
    const int bc = blockIdx.x;           // 0 .. B*C-1, one (batch,channel) plane
    const int b  = bc >> 8;              // / CC (CC == 256)
    const int c  = bc & (CC - 1);

    const float lo = lov[c];
    const float hi = hiv[c];
    const int   k  = inv[c];

    const float4* mp = (const float4*)(mainp + (size_t)bc * HWN);
    float4*       op = (float4*)(out   + (size_t)bc * HWN);

    if (k >= 0) {
        // vulnerable channel: combine main with dup per reference select chain
        const float4* dp = (const float4*)(dupp + ((size_t)b * K + k) * HWN);
        for (int j = threadIdx.x; j < HW4; j += 256) {
            float4 m = mp[j];
            float4 d = dp[j];
            float4 r;
            #pragma unroll
            for (int e = 0; e < 4; ++e) {
                float x = ((const float*)&m)[e];
                float y = ((const float*)&d)[e];
                if (x != x) x = 0.0f;            // nan_to_num
                if (y != y) y = 0.0f;
                bool mv = (x >= lo) && (x <= hi);
                bool dv = (y >= lo) && (y <= hi);
                float res = (mv && dv && (x != y)) ? fminf(x, y)
                          : ((dv && !mv) ? y
                          : (mv ? x : 0.0f));
                ((float*)&r)[e] = res;
            }
            op[j] = r;
        }
    } else {
        // plain channel: clamp-to-zero outside [lo, hi]
        for (int j = threadIdx.x; j < HW4; j += 256) {
            float4 m = mp[j];
            float4 r;
            #pragma unroll
            for (int e = 0; e < 4; ++e) {
                float x = ((const float*)&m)[e];
                if (x != x) x = 0.0f;
                bool mv = (x >= lo) && (x <= hi);
                ((float*)&r)[e] = mv ? x : 0.0f;
            }
            op[j] = r;
        }
    }
}

extern "C" void kernel_launch(void* const* d_in, const int* in_sizes, int n_in,
                              void* d_out, int out_size, void* d_ws, size_t ws_size,
                              hipStream_t stream) {
    const float* mainp = (const float*)d_in[0];
    const float* dupp  = (const float*)d_in[1];
    const float* lov   = (const float*)d_in[2];
    const float* hiv   = (const float*)d_in[3];
    const int*   vidx  = (const int*)d_in[4];
    const int    K     = in_sizes[4];

    int* inv = (int*)d_ws;   // C ints of scratch; rebuilt every call (ws is re-poisoned)

    hipLaunchKernelGGL(build_inv_kernel, dim3(1), dim3(CC), 0, stream,
                       vidx, K, inv);
    hipLaunchKernelGGL(edac_kernel, dim3(BB * CC), dim3(256), 0, stream,
                       mainp, dupp, lov, hiv, inv, (float*)d_out, K);
}

// Round 3
// 206.271 us; speedup vs baseline: 1.0165x; 1.0165x over previous
//
#include <hip/hip_runtime.h>

// Problem constants (B, C, K, H, W) = (32, 256, 64, 56, 56)
constexpr int BB  = 32;
constexpr int CC  = 256;
constexpr int HWN = 56 * 56;      // 3136 elements per channel plane
constexpr int HW4 = HWN / 4;      // 784 float4 per plane (= 3*256 + 16)

// Native clang vector type — required by __builtin_nontemporal_store and
// guarantees dwordx4 codegen.
typedef float v4f __attribute__((ext_vector_type(4)));

__device__ __forceinline__ float edac_pair(float x, float y, float lo, float hi) {
    if (x != x) x = 0.0f;            // nan_to_num
    if (y != y) y = 0.0f;
    bool mv = (x >= lo) && (x <= hi);
    bool dv = (y >= lo) && (y <= hi);
    return (mv && dv && (x != y)) ? fminf(x, y)
         : ((dv && !mv) ? y
         : (mv ? x : 0.0f));
}

__device__ __forceinline__ float edac_single(float x, float lo, float hi) {
    if (x != x) x = 0.0f;
    bool mv = (x >= lo) && (x <= hi);
    return mv ? x : 0.0f;
}

__global__ __launch_bounds__(256) void edac_kernel(
    const float* __restrict__ mainp,
    const float* __restrict__ dupp,
    const float* __restrict__ lov,
    const float* __restrict__ hiv,
    const int*   __restrict__ vidx,
    float*       __restrict__ out,
    int K)
{
    const int bc = blockIdx.x;           // 0 .. B*C-1, one (batch,channel) plane
    const int b  = bc >> 8;              // / CC (CC == 256)
    const int c  = bc & (CC - 1);
    const int t  = threadIdx.x;

    // Per-block search: k = position of c in vidx (or -1). vidx is 256 B,
    // L2-resident; replaces a separate build_inv launch.
    __shared__ int sk;
    if (t == 0) sk = -1;
    __syncthreads();
    if (t < K && vidx[t] == c) sk = t;
    __syncthreads();
    const int k = sk;

    const float lo = lov[c];
    const float hi = hiv[c];

    const v4f* mp = (const v4f*)(mainp + (size_t)bc * HWN);
    v4f*       op = (v4f*)(out   + (size_t)bc * HWN);

    // 784 float4 per plane: every thread handles j = t, t+256, t+512;
    // threads 0..15 also handle t+768. Issue ALL loads up front
    // (independent -> multiple outstanding 1KB wave-loads), compute, NT-store.
    const bool extra = (t < HW4 - 3 * 256);   // t < 16

    v4f m0 = mp[t];
    v4f m1 = mp[t + 256];
    v4f m2 = mp[t + 512];
    v4f m3 = extra ? mp[t + 768] : (v4f)(0.0f);

    if (k >= 0) {
        const v4f* dp = (const v4f*)(dupp + ((size_t)b * K + k) * HWN);
        v4f d0 = dp[t];
        v4f d1 = dp[t + 256];
        v4f d2 = dp[t + 512];
        v4f d3 = extra ? dp[t + 768] : (v4f)(0.0f);

        v4f r0, r1, r2, r3;
        #pragma unroll
        for (int e = 0; e < 4; ++e) {
            r0[e] = edac_pair(m0[e], d0[e], lo, hi);
            r1[e] = edac_pair(m1[e], d1[e], lo, hi);
            r2[e] = edac_pair(m2[e], d2[e], lo, hi);
            r3[e] = edac_pair(m3[e], d3[e], lo, hi);
        }
        __builtin_nontemporal_store(r0, &op[t]);
        __builtin_nontemporal_store(r1, &op[t + 256]);
        __builtin_nontemporal_store(r2, &op[t + 512]);
        if (extra) __builtin_nontemporal_store(r3, &op[t + 768]);
    } else {
        v4f r0, r1, r2, r3;
        #pragma unroll
        for (int e = 0; e < 4; ++e) {
            r0[e] = edac_single(m0[e], lo, hi);
            r1[e] = edac_single(m1[e], lo, hi);
            r2[e] = edac_single(m2[e], lo, hi);
            r3[e] = edac_single(m3[e], lo, hi);
        }
        __builtin_nontemporal_store(r0, &op[t]);
        __builtin_nontemporal_store(r1, &op[t + 256]);
        __builtin_nontemporal_store(r2, &op[t + 512]);
        if (extra) __builtin_nontemporal_store(r3, &op[t + 768]);
    }
}

extern "C" void kernel_launch(void* const* d_in, const int* in_sizes, int n_in,
                              void* d_out, int out_size, void* d_ws, size_t ws_size,
                              hipStream_t stream) {
    const float* mainp = (const float*)d_in[0];
    const float* dupp  = (const float*)d_in[1];
    const float* lov   = (const float*)d_in[2];
    const float* hiv   = (const float*)d_in[3];
    const int*   vidx  = (const int*)d_in[4];
    const int    K     = in_sizes[4];

    hipLaunchKernelGGL(edac_kernel, dim3(BB * CC), dim3(256), 0, stream,
                       mainp, dupp, lov, hiv, vidx, (float*)d_out, K);
}

// Round 4
// 199.654 us; speedup vs baseline: 1.0501x; 1.0331x over previous
//
#include <hip/hip_runtime.h>

// Problem constants (B, C, K, H, W) = (32, 256, 64, 56, 56)
constexpr int BB  = 32;
constexpr int CC  = 256;
constexpr int HWN = 56 * 56;      // 3136 elements per channel plane
constexpr int HW4 = HWN / 4;      // 784 float4 per plane (= 3*256 + 16)

constexpr int NPLANE = 4;                  // planes per block
constexpr int GRID   = BB * CC / NPLANE;   // 2048 blocks, persistent-ish

// Native clang vector type — required by nontemporal builtins, guarantees dwordx4.
typedef float v4f __attribute__((ext_vector_type(4)));

__device__ __forceinline__ float edac_pair(float x, float y, float lo, float hi) {
    if (x != x) x = 0.0f;            // nan_to_num
    if (y != y) y = 0.0f;
    bool mv = (x >= lo) && (x <= hi);
    bool dv = (y >= lo) && (y <= hi);
    return (mv && dv && (x != y)) ? fminf(x, y)
         : ((dv && !mv) ? y
         : (mv ? x : 0.0f));
}

__device__ __forceinline__ float edac_single(float x, float lo, float hi) {
    if (x != x) x = 0.0f;
    return ((x >= lo) && (x <= hi)) ? x : 0.0f;
}

__device__ __forceinline__ void load_plane(const float* p, int t, bool extra,
                                           v4f& x0, v4f& x1, v4f& x2, v4f& x3) {
    const v4f* vp = (const v4f*)p;
    x0 = __builtin_nontemporal_load(&vp[t]);
    x1 = __builtin_nontemporal_load(&vp[t + 256]);
    x2 = __builtin_nontemporal_load(&vp[t + 512]);
    x3 = extra ? __builtin_nontemporal_load(&vp[t + 768]) : (v4f)(0.0f);
}

__device__ __forceinline__ void store_plane(float* p, int t, bool extra,
                                            v4f r0, v4f r1, v4f r2, v4f r3) {
    v4f* vp = (v4f*)p;
    __builtin_nontemporal_store(r0, &vp[t]);
    __builtin_nontemporal_store(r1, &vp[t + 256]);
    __builtin_nontemporal_store(r2, &vp[t + 512]);
    if (extra) __builtin_nontemporal_store(r3, &vp[t + 768]);
}

__global__ __launch_bounds__(256) void edac_kernel(
    const float* __restrict__ mainp,
    const float* __restrict__ dupp,
    const float* __restrict__ lov,
    const float* __restrict__ hiv,
    const int*   __restrict__ vidx,
    float*       __restrict__ out,
    int K)
{
    const int bid = blockIdx.x;          // 0..2047
    const int c   = bid & (CC - 1);      // GRID % CC == 0 -> same c for all 4 planes
    const int b0  = bid >> 8;            // batches b0, b0+8, b0+16, b0+24
    const int t   = threadIdx.x;

    // One vidx search per block (covers all 4 planes: same channel).
    __shared__ int sk;
    if (t == 0) sk = -1;
    __syncthreads();
    if (t < K && vidx[t] == c) sk = t;
    __syncthreads();
    const int k = sk;

    const float lo = lov[c];
    const float hi = hiv[c];
    const bool extra = (t < HW4 - 3 * 256);   // t < 16

    const size_t step = (size_t)GRID * HWN;   // plane stride in floats (same for out)
    const float* mb = mainp + (size_t)bid * HWN;
    float*       ob = out   + (size_t)bid * HWN;

    if (k >= 0) {
        const size_t dstep = (size_t)(BB / NPLANE) * K * HWN;  // batch stride 8 in dup
        const float* db = dupp + ((size_t)b0 * K + k) * HWN;

        v4f a0, a1, a2, a3, da0, da1, da2, da3;
        load_plane(mb, t, extra, a0, a1, a2, a3);
        load_plane(db, t, extra, da0, da1, da2, da3);

        #pragma unroll
        for (int i = 0; i < NPLANE; ++i) {
            v4f n0, n1, n2, n3, nd0, nd1, nd2, nd3;
            if (i + 1 < NPLANE) {
                load_plane(mb + (size_t)(i + 1) * step,  t, extra, n0, n1, n2, n3);
                load_plane(db + (size_t)(i + 1) * dstep, t, extra, nd0, nd1, nd2, nd3);
            }
            v4f r0, r1, r2, r3;
            #pragma unroll
            for (int e = 0; e < 4; ++e) {
                r0[e] = edac_pair(a0[e], da0[e], lo, hi);
                r1[e] = edac_pair(a1[e], da1[e], lo, hi);
                r2[e] = edac_pair(a2[e], da2[e], lo, hi);
                r3[e] = edac_pair(a3[e], da3[e], lo, hi);
            }
            store_plane(ob + (size_t)i * step, t, extra, r0, r1, r2, r3);
            a0 = n0; a1 = n1; a2 = n2; a3 = n3;
            da0 = nd0; da1 = nd1; da2 = nd2; da3 = nd3;
        }
    } else {
        v4f a0, a1, a2, a3;
        load_plane(mb, t, extra, a0, a1, a2, a3);

        #pragma unroll
        for (int i = 0; i < NPLANE; ++i) {
            v4f n0, n1, n2, n3;
            if (i + 1 < NPLANE) {
                load_plane(mb + (size_t)(i + 1) * step, t, extra, n0, n1, n2, n3);
            }
            v4f r0, r1, r2, r3;
            #pragma unroll
            for (int e = 0; e < 4; ++e) {
                r0[e] = edac_single(a0[e], lo, hi);
                r1[e] = edac_single(a1[e], lo, hi);
                r2[e] = edac_single(a2[e], lo, hi);
                r3[e] = edac_single(a3[e], lo, hi);
            }
            store_plane(ob + (size_t)i * step, t, extra, r0, r1, r2, r3);
            a0 = n0; a1 = n1; a2 = n2; a3 = n3;
        }
    }
}

extern "C" void kernel_launch(void* const* d_in, const int* in_sizes, int n_in,
                              void* d_out, int out_size, void* d_ws, size_t ws_size,
                              hipStream_t stream) {
    const float* mainp = (const float*)d_in[0];
    const float* dupp  = (const float*)d_in[1];
    const float* lov   = (const float*)d_in[2];
    const float* hiv   = (const float*)d_in[3];
    const int*   vidx  = (const int*)d_in[4];
    const int    K     = in_sizes[4];

    hipLaunchKernelGGL(edac_kernel, dim3(GRID), dim3(256), 0, stream,
                       mainp, dupp, lov, hiv, vidx, (float*)d_out, K);
}